// Round 14
// baseline (219.792 us; speedup 1.0000x reference)
//
#include <hip/hip_runtime.h>
#include <hip/hip_bf16.h>
#include <math.h>

namespace {
constexpr int M  = 48;    // fields
constexpr int D  = 128;   // embedding dim
constexpr int DH = 64;    // d's per block (d-half)
constexpr int H1 = 68;
constexpr int H2 = 32;
constexpr int H3 = 24;
constexpr int K1 = M  * M;   // 2304
constexpr int K2 = H1 * M;   // 3264
constexpr int K3 = H2 * M;   // 1536
constexpr int HOP1 = 80;     // H1 padded to 5 N-tiles of 16
constexpr int HOP2 = 32;
constexpr int HOP3 = 32;
// ws layout (ushort elements for weights, then float arrays)
constexpr int E1 = (K1 / 8) * HOP1 * 8;   // 184320
constexpr int E2 = (K2 / 8) * HOP2 * 8;   // 104448
constexpr int E3 = (K3 / 8) * HOP3 * 8;   //  49152
constexpr int EF = (M * D) * 64;          // 393216  fc1_w bf16
constexpr int EW = E1 + E2 + E3 + EF;     // 731136 ushorts
// float region offsets (in floats, from wsf base)
constexpr int OPOOL = 0;                  // ppool[1024][128]
constexpr int OH1P  = 1024 * 128;         // h1p[1024][64]
constexpr int X0S = 52;  // x0T fp32 stride
constexpr int BAS = 69;  // bufA f16 stride
constexpr int BBS = 33;  // bufB f16 stride
constexpr float BN_SCALE = 0.9995003746877732f;  // 1/sqrt(1+1e-3)
// prep thread-space
constexpr int P1 = (K1 / 8) * HOP1;  // 23040
constexpr int P2 = (K2 / 8) * HOP2;  // 13056
constexpr int P3 = (K3 / 8) * HOP3;  //  6144
constexpr int P4 = EF / 8;           // 49152
}

typedef __attribute__((ext_vector_type(8))) _Float16 half8;
typedef __attribute__((ext_vector_type(2))) __fp16   fp16x2;   // cvt_pkrtz result type
typedef __attribute__((ext_vector_type(4))) float f32x4;
typedef __attribute__((ext_vector_type(8))) unsigned short us8;

static __device__ __forceinline__ unsigned short f2bs(float f) {  // bf16 RNE (fc1 path)
    __hip_bfloat16 h = __float2bfloat16(f);
    return __builtin_bit_cast(unsigned short, h);
}
static __device__ __forceinline__ unsigned short f2hs(float f) {  // f16 RNE
    _Float16 h = (_Float16)f;
    return __builtin_bit_cast(unsigned short, h);
}
static __device__ __forceinline__ float hs2f(unsigned short u) {  // f16 -> f32
    return (float)__builtin_bit_cast(_Float16, u);
}
// packed fp32x2 -> f16x2 convert (RTZ): ONE VALU instruction (hot path)
static __device__ __forceinline__ unsigned int cvt2(float a, float b) {
    fp16x2 h = __builtin_amdgcn_cvt_pkrtz(a, b);
    return __builtin_bit_cast(unsigned int, h);
}

// ---------------- prep: transpose+convert weights into d_ws ------------------
// n8-major: ws[n8*HOP*8 + o*8 + i] = W[n8*8+i][o] (o<HOP pad 0), f16 for MFMA.
// fc1_w stays bf16 (shift-based unpack in fc1 partial).
__global__ __launch_bounds__(256)
void prep_kernel(const float* __restrict__ w1, const float* __restrict__ w2,
                 const float* __restrict__ w3, const float* __restrict__ fc1w,
                 unsigned short* __restrict__ ws)
{
    const int tid = blockIdx.x * 256 + threadIdx.x;
    us8 v;
    if (tid < P1) {
        const int k8 = tid / HOP1, o = tid - k8 * HOP1;
        #pragma unroll
        for (int i = 0; i < 8; ++i)
            v[i] = (o < H1) ? f2hs(w1[(k8 * 8 + i) * H1 + o]) : (unsigned short)0;
        *(uint4*)(ws + (size_t)k8 * (HOP1 * 8) + o * 8) = __builtin_bit_cast(uint4, v);
    } else if (tid < P1 + P2) {
        const int x = tid - P1;
        const int k8 = x >> 5, o = x & 31;
        #pragma unroll
        for (int i = 0; i < 8; ++i)
            v[i] = f2hs(w2[(k8 * 8 + i) * H2 + o]);
        *(uint4*)(ws + E1 + (size_t)k8 * (HOP2 * 8) + o * 8) = __builtin_bit_cast(uint4, v);
    } else if (tid < P1 + P2 + P3) {
        const int x = tid - (P1 + P2);
        const int k8 = x >> 5, o = x & 31;
        #pragma unroll
        for (int i = 0; i < 8; ++i)
            v[i] = (o < H3) ? f2hs(w3[(k8 * 8 + i) * H3 + o]) : (unsigned short)0;
        *(uint4*)(ws + E1 + E2 + (size_t)k8 * (HOP3 * 8) + o * 8) = __builtin_bit_cast(uint4, v);
    } else if (tid < P1 + P2 + P3 + P4) {
        const int x = tid - (P1 + P2 + P3);
        const float4 a = ((const float4*)fc1w)[x * 2];
        const float4 b = ((const float4*)fc1w)[x * 2 + 1];
        v[0] = f2bs(a.x); v[1] = f2bs(a.y); v[2] = f2bs(a.z); v[3] = f2bs(a.w);
        v[4] = f2bs(b.x); v[5] = f2bs(b.y); v[6] = f2bs(b.z); v[7] = f2bs(b.w);
        *(uint4*)(ws + E1 + E2 + E3 + (size_t)x * 8) = __builtin_bit_cast(uint4, v);
    }
}

// ---------------- CIN layer via 16x16x32 f16 MFMA; block = (b, d-half) -------
// C[d][o] = sum_n A[d][n]*W[n][o], n = k*48+j, A[d][n] = xk[d][k]*x0T[d][j].
// MFMA 16x16x32: A row = lane&15, n-slice = (lane>>4)*8+i; C col = lane&15,
// row = (lane>>4)*4+reg (m89-verified). n8 = ks*4+quad; t6 = 4p+quad (p=ks%3)
// -> kbase[p] = t6/6, j0[p] = (t6%6)*8: 3 fixed (qa,qb) pairs per layer,
// k = 4*(ks/6)+2*((ks%6)>=3)+kbase[p] — all affine.
// 4 waves = 4 d-tiles of 16 rows, each FULL K range -> all waves issue the
// IDENTICAL B address stream: first wave misses to L2, the rest hit L1, and
// lagging waves speed up (hits) while leaders slow (misses) — self-aligning.
// No khalf combine; waves fully independent within a layer; one barrier per
// layer boundary re-aligns the pack.
// NO device-scope fences (per-XCD L2 writeback — R10 regression).
template<int KTOT, int HO, int NT, int HOP, bool XKF16, bool WRITEBUF>
__device__ __forceinline__ void cin_mfma(
    const float* __restrict__ x0T,
    const void*  __restrict__ xksrc, int xkstride,
    const unsigned short* __restrict__ wt,
    unsigned short* __restrict__ outbuf, int outstride,
    float* __restrict__ pool, int poff, int t)
{
    const int lane = t & 63, w4 = t >> 6;
    const int m = lane & 15, quad = lane >> 4;
    const int dl = w4 * 16 + m;           // this lane's A-row (local d)
    constexpr int KS = KTOT / 32;
    static_assert(KS % 6 == 0, "KS must be a multiple of 6");

    // per-phase invariants (p = ks % 3)
    int kbase[3], j0[3];
    #pragma unroll
    for (int p = 0; p < 3; ++p) {
        const int t6 = p * 4 + quad;      // 0..11
        kbase[p] = t6 / 6;                // 0 or 1
        j0[p]    = (t6 - 6 * kbase[p]) * 8;
    }
    // x0 j-operands: 3 fixed register pairs for the whole layer
    float4 qa[3], qb[3];
    #pragma unroll
    for (int p = 0; p < 3; ++p) {
        qa[p] = *(const float4*)(x0T + dl * X0S + j0[p]);
        qb[p] = *(const float4*)(x0T + dl * X0S + j0[p] + 4);
    }

    f32x4 acc[NT];
    #pragma unroll
    for (int nt = 0; nt < NT; ++nt) acc[nt] = (f32x4){0.f, 0.f, 0.f, 0.f};

    const float*          xkrowf = (const float*)xksrc + dl * xkstride;
    const unsigned short* xkrowh = (const unsigned short*)xksrc + dl * xkstride;
    const unsigned short* wb = wt + (size_t)(quad * HOP + m) * 8;

    auto xkload = [&](int k) -> float {
        return XKF16 ? hs2f(xkrowh[k]) : xkrowf[k];
    };

    uint4 brA[NT], brB[NT];
    auto loadB = [&](int ks, uint4* br) {
        const unsigned short* p = wb + (size_t)ks * (4 * HOP * 8);
        #pragma unroll
        for (int nt = 0; nt < NT; ++nt)
            br[nt] = *(const uint4*)(p + nt * 128);
    };
    auto phase = [&](int p, float xv, const uint4* br) {
        uint4 u;
        u.x = cvt2(xv * qa[p].x, xv * qa[p].y);
        u.y = cvt2(xv * qa[p].z, xv * qa[p].w);
        u.z = cvt2(xv * qb[p].x, xv * qb[p].y);
        u.w = cvt2(xv * qb[p].z, xv * qb[p].w);
        const half8 av = __builtin_bit_cast(half8, u);
        #pragma unroll
        for (int nt = 0; nt < NT; ++nt)
            acc[nt] = __builtin_amdgcn_mfma_f32_16x16x32_f16(
                av, __builtin_bit_cast(half8, br[nt]), acc[nt], 0, 0, 0);
    };

    loadB(0, brA);
    loadB(1, brB);
    #pragma unroll 1
    for (int it = 0; it < KS / 6; ++it) {
        const int g  = it * 6;
        const int kk = it * 4;
        const float xv0 = xkload(kk + kbase[0]);
        const float xv1 = xkload(kk + kbase[1]);
        const float xv2 = xkload(kk + kbase[2]);
        phase(0, xv0, brA);  loadB(g + 2, brA);
        phase(1, xv1, brB);  loadB(g + 3, brB);
        phase(2, xv2, brA);  loadB(g + 4, brA);
        const float xv3 = xkload(kk + 2 + kbase[0]);
        const float xv4 = xkload(kk + 2 + kbase[1]);
        const float xv5 = xkload(kk + 2 + kbase[2]);
        phase(0, xv3, brB);  loadB(g + 5, brB);
        phase(1, xv4, brA);  loadB(g + 6, brA);   // final iter: <=2 ksteps past
        phase(2, xv5, brB);  loadB(g + 7, brB);   // layer region, inside d_ws
    }

    // epilogue: C row = quad*4+reg (local d within tile), col = m (o within nt)
    const int dbase = w4 * 16 + quad * 4;
    #pragma unroll
    for (int nt = 0; nt < NT; ++nt) {
        const int o = nt * 16 + m;
        if (o < HO) {
            const f32x4 a = acc[nt];
            if (WRITEBUF) {
                outbuf[(dbase + 0) * outstride + o] = f2hs(a.x);
                outbuf[(dbase + 1) * outstride + o] = f2hs(a.y);
                outbuf[(dbase + 2) * outstride + o] = f2hs(a.z);
                outbuf[(dbase + 3) * outstride + o] = f2hs(a.w);
            }
            float s = a.x + a.y + a.z + a.w;
            s += __shfl_xor(s, 16, 64);
            s += __shfl_xor(s, 32, 64);
            if (lane < 16) atomicAdd(&pool[poff + o], s);
        }
    }
}

__global__ __launch_bounds__(256, 4)
void dcin_kernel(const int*   __restrict__ x,
                 const float* __restrict__ emb,
                 const unsigned short* __restrict__ ws,   // f16/bf16 weights
                 float* __restrict__ wsf)                 // float partial region
{
    __shared__ float x0T [DH * X0S];                          // 13312 B fp32 embeds
    __shared__ __align__(16) unsigned short bufA[DH * BAS];   //  8832 B f16 L1 out
    __shared__ __align__(16) unsigned short bufB[DH * BBS];   //  4224 B f16 L2 out
    __shared__ float pool_s[H1 + H2 + H3];
    __shared__ int   sx[M];
    float* const red2 = (float*)bufB;    // 512 floats (2048B <= 4224B), after layer 3

    const unsigned short* wt1  = ws;
    const unsigned short* wt2  = ws + E1;
    const unsigned short* wt3  = ws + E1 + E2;
    const unsigned short* fc1b = ws + E1 + E2 + E3;

    const int b = blockIdx.x >> 1;
    const int h = blockIdx.x & 1;      // d-half
    const int t = threadIdx.x;

    if (t < M) sx[t] = x[b * M + t];
    if (t < H1 + H2 + H3) pool_s[t] = 0.f;
    __syncthreads();

    // gather x0T[dl][j] = emb[sx[j]][h*64+dl]; j-fast: stride-1 dw LDS writes
    for (int i = t; i < M * (DH / 4); i += 256) {
        const int c = i / 48;              // local float4 index 0..15
        const int j = i - c * 48;
        const float4 v = ((const float4*)(emb + (size_t)sx[j] * D))[h * 16 + c];
        x0T[(4 * c + 0) * X0S + j] = v.x;
        x0T[(4 * c + 1) * X0S + j] = v.y;
        x0T[(4 * c + 2) * X0S + j] = v.z;
        x0T[(4 * c + 3) * X0S + j] = v.w;
    }
    __syncthreads();

    // ---- CIN layers (16x16x32 f16 MFMA); waves independent per layer; one
    // barrier per boundary re-aligns the pack for the L1 same-stream effect ----
    cin_mfma<K1, H1, 5, HOP1, false, true >(x0T, x0T,  X0S, wt1, bufA, BAS, pool_s, 0, t);
    __syncthreads();
    cin_mfma<K2, H2, 2, HOP2, true,  true >(x0T, bufA, BAS, wt2, bufB, BBS, pool_s, H1, t);
    __syncthreads();
    cin_mfma<K3, H3, 2, HOP3, true,  false>(x0T, bufB, BBS, wt3, nullptr, 0, pool_s, H1 + H2, t);
    __syncthreads();   // pool complete, bufB (red2 alias) dead

    // ---- fc1 partial for this d-half (bf16 weights), no bias/act ----
    {
        const int u2 = (t & 31) * 2;
        const int part = t >> 5;          // 8 parts x 6 fields
        float a0 = 0.f, a1 = 0.f;
        for (int j = part * 6; j < part * 6 + 6; ++j) {
            const float* xr = x0T + j;
            #pragma unroll 4
            for (int d = 0; d < DH; ++d) {
                const float xv = xr[d * X0S];
                const unsigned int wp = *(const unsigned int*)(
                    fc1b + (size_t)(j * D + h * DH + d) * 64 + u2);
                a0 = fmaf(xv, __builtin_bit_cast(float, wp << 16), a0);
                a1 = fmaf(xv, __builtin_bit_cast(float, wp & 0xffff0000u), a1);
            }
        }
        red2[t * 2]     = a0;
        red2[t * 2 + 1] = a1;
    }
    __syncthreads();

    // ---- store partials to global ----
    const int slot = b * 2 + h;
    if (t < 64) {
        float v = 0.f;
        #pragma unroll
        for (int p = 0; p < 8; ++p)
            v += red2[(p * 32 + (t >> 1)) * 2 + (t & 1)];
        wsf[OH1P + slot * 64 + t] = v;
    }
    if (t >= 64 && t < 64 + H1 + H2 + H3)
        wsf[OPOOL + slot * 128 + (t - 64)] = pool_s[t - 64];
}

// ---------------- tail: combine halves + fc chain + output -------------------
__global__ __launch_bounds__(64)
void tail_kernel(const int*   __restrict__ x,
                 const float* __restrict__ lin_w, const float* __restrict__ lin_b,
                 const float* __restrict__ fc1_b,
                 const float* __restrict__ bn1_g, const float* __restrict__ bn1_b,
                 const float* __restrict__ fc2_w, const float* __restrict__ fc2_b,
                 const float* __restrict__ bn2_g, const float* __restrict__ bn2_b,
                 const float* __restrict__ fc3_w, const float* __restrict__ fc3_b,
                 const float* __restrict__ bn3_g, const float* __restrict__ bn3_b,
                 const float* __restrict__ out_w, const float* __restrict__ out_b,
                 const float* __restrict__ wsf,
                 float* __restrict__ out)
{
    __shared__ float h1s[64], h2s[48], h3s[24];
    __shared__ float pool_s[H1 + H2 + H3];
    const int b = blockIdx.x;
    const int t = threadIdx.x;
    const int s0 = b * 2, s1 = b * 2 + 1;

    {
        float v = wsf[OH1P + s0 * 64 + t] + wsf[OH1P + s1 * 64 + t] + fc1_b[t];
        v = fmaxf(v, 0.f);
        h1s[t] = bn1_g[t] * v * BN_SCALE + bn1_b[t];
    }
    for (int i = t; i < H1 + H2 + H3; i += 64)
        pool_s[i] = wsf[OPOOL + s0 * 128 + i] + wsf[OPOOL + s1 * 128 + i];
    __syncthreads();

    if (t < 48) {
        float a = fc2_b[t];
        #pragma unroll 4
        for (int u = 0; u < 64; ++u) a = fmaf(h1s[u], fc2_w[u * 48 + t], a);
        a = tanhf(a);
        h2s[t] = bn2_g[t] * a * BN_SCALE + bn2_b[t];
    }
    __syncthreads();

    if (t < 24) {
        float a = fc3_b[t];
        #pragma unroll 4
        for (int u = 0; u < 48; ++u) a = fmaf(h2s[u], fc3_w[u * 24 + t], a);
        a = tanhf(a);
        h3s[t] = bn3_g[t] * a * BN_SCALE + bn3_b[t];
    }
    __syncthreads();

    if (t == 0) {
        float s = lin_b[0];
        for (int j = 0; j < M; ++j) s += (float)x[b * M + j] * lin_w[j];
        const float slin = tanhf(s);
        float z = out_b[0];
        #pragma unroll 4
        for (int i = 0; i < H3; ++i) z = fmaf(h3s[i], out_w[i], z);
        z = fmaf(slin, out_w[H3], z);
        #pragma unroll 4
        for (int i = 0; i < H1 + H2 + H3; ++i)
            z = fmaf(pool_s[i], out_w[H3 + 1 + i], z);
        out[b] = 1.f / (1.f + expf(-z));
    }
}

extern "C" void kernel_launch(void* const* d_in, const int* in_sizes, int n_in,
                              void* d_out, int out_size, void* d_ws, size_t ws_size,
                              hipStream_t stream) {
    (void)in_sizes; (void)n_in; (void)ws_size; (void)out_size;
    const int*   x     = (const int*)  d_in[0];
    const float* emb   = (const float*)d_in[1];
    const float* w1    = (const float*)d_in[2];
    const float* w2    = (const float*)d_in[3];
    const float* w3    = (const float*)d_in[4];
    const float* lin_w = (const float*)d_in[5];
    const float* lin_b = (const float*)d_in[6];
    const float* fc1_w = (const float*)d_in[7];
    const float* fc1_b = (const float*)d_in[8];
    const float* bn1_g = (const float*)d_in[9];
    const float* bn1_b = (const float*)d_in[10];
    const float* fc2_w = (const float*)d_in[11];
    const float* fc2_b = (const float*)d_in[12];
    const float* bn2_g = (const float*)d_in[13];
    const float* bn2_b = (const float*)d_in[14];
    const float* fc3_w = (const float*)d_in[15];
    const float* fc3_b = (const float*)d_in[16];
    const float* bn3_g = (const float*)d_in[17];
    const float* bn3_b = (const float*)d_in[18];
    const float* out_w = (const float*)d_in[19];
    const float* out_b = (const float*)d_in[20];
    unsigned short* ws = (unsigned short*)d_ws;
    float* wsf = (float*)(ws + EW);

    const int prep_threads = P1 + P2 + P3 + P4;
    prep_kernel<<<(prep_threads + 255) / 256, 256, 0, stream>>>(w1, w2, w3, fc1_w, ws);

    dcin_kernel<<<1024, 256, 0, stream>>>(x, emb, ws, wsf);

    tail_kernel<<<512, 64, 0, stream>>>(
        x, lin_w, lin_b, fc1_b, bn1_g, bn1_b,
        fc2_w, fc2_b, bn2_g, bn2_b,
        fc3_w, fc3_b, bn3_g, bn3_b,
        out_w, out_b, wsf, (float*)d_out);
}

// Round 15
// 196.958 us; speedup vs baseline: 1.1159x; 1.1159x over previous
//
#include <hip/hip_runtime.h>
#include <hip/hip_bf16.h>
#include <math.h>

namespace {
constexpr int M  = 48;    // fields
constexpr int D  = 128;   // embedding dim
constexpr int DH = 64;    // d's per block (d-half)
constexpr int H1 = 68;
constexpr int H2 = 32;
constexpr int H3 = 24;
constexpr int K1 = M  * M;   // 2304
constexpr int K2 = H1 * M;   // 3264
constexpr int K3 = H2 * M;   // 1536
constexpr int HOP1 = 96;     // H1 padded to 3 N-tiles of 32
constexpr int HOP2 = 32;
constexpr int HOP3 = 32;
// ws layout (ushort elements for weights, then float arrays)
constexpr int E1 = (K1 / 8) * HOP1 * 8;   // 221184
constexpr int E2 = (K2 / 8) * HOP2 * 8;   // 104448
constexpr int E3 = (K3 / 8) * HOP3 * 8;   //  49152
constexpr int EF = (M * D) * 64;          // 393216  fc1_w bf16
constexpr int EW = E1 + E2 + E3 + EF;     // 768000 ushorts
// float region offsets (in floats, from wsf base)
constexpr int OPOOL = 0;                  // ppool[1024][128]
constexpr int OH1P  = 1024 * 128;         // h1p[1024][64]
constexpr int X0S = 56;  // x0h f16 stride (112 B rows -> 16B-aligned half8 loads)
constexpr int BAS = 69;  // bufA f16 stride
constexpr int BBS = 33;  // bufB f16 stride
constexpr float BN_SCALE = 0.9995003746877732f;  // 1/sqrt(1+1e-3)
// prep thread-space
constexpr int P1 = (K1 / 8) * HOP1;  // 27648
constexpr int P2 = (K2 / 8) * HOP2;  // 13056
constexpr int P3 = (K3 / 8) * HOP3;  //  6144
constexpr int P4 = EF / 8;           // 49152
}

typedef __attribute__((ext_vector_type(8)))  _Float16 half8;
typedef __attribute__((ext_vector_type(2)))  __fp16   fp16x2;
typedef __attribute__((ext_vector_type(16))) float f32x16;
typedef __attribute__((ext_vector_type(8)))  unsigned short us8;

static __device__ __forceinline__ unsigned short f2bs(float f) {  // bf16 RNE (fc1 path)
    __hip_bfloat16 h = __float2bfloat16(f);
    return __builtin_bit_cast(unsigned short, h);
}
static __device__ __forceinline__ unsigned short f2hs(float f) {  // f16 RNE
    _Float16 h = (_Float16)f;
    return __builtin_bit_cast(unsigned short, h);
}
static __device__ __forceinline__ float hs2f(unsigned short u) {  // f16 -> f32
    return (float)__builtin_bit_cast(_Float16, u);
}

// ---------------- prep: transpose+convert weights into d_ws ------------------
// n8-major: ws[n8*HOP*8 + o*8 + i] = W[n8*8+i][o] (o<HOP pad 0), f16 for MFMA.
// fc1_w stays bf16 (shift-based unpack in fc1 partial).
__global__ __launch_bounds__(256)
void prep_kernel(const float* __restrict__ w1, const float* __restrict__ w2,
                 const float* __restrict__ w3, const float* __restrict__ fc1w,
                 unsigned short* __restrict__ ws)
{
    const int tid = blockIdx.x * 256 + threadIdx.x;
    us8 v;
    if (tid < P1) {
        const int k8 = tid / HOP1, o = tid - k8 * HOP1;
        #pragma unroll
        for (int i = 0; i < 8; ++i)
            v[i] = (o < H1) ? f2hs(w1[(k8 * 8 + i) * H1 + o]) : (unsigned short)0;
        *(uint4*)(ws + (size_t)k8 * (HOP1 * 8) + o * 8) = __builtin_bit_cast(uint4, v);
    } else if (tid < P1 + P2) {
        const int x = tid - P1;
        const int k8 = x >> 5, o = x & 31;
        #pragma unroll
        for (int i = 0; i < 8; ++i)
            v[i] = f2hs(w2[(k8 * 8 + i) * H2 + o]);
        *(uint4*)(ws + E1 + (size_t)k8 * (HOP2 * 8) + o * 8) = __builtin_bit_cast(uint4, v);
    } else if (tid < P1 + P2 + P3) {
        const int x = tid - (P1 + P2);
        const int k8 = x >> 5, o = x & 31;
        #pragma unroll
        for (int i = 0; i < 8; ++i)
            v[i] = (o < H3) ? f2hs(w3[(k8 * 8 + i) * H3 + o]) : (unsigned short)0;
        *(uint4*)(ws + E1 + E2 + (size_t)k8 * (HOP3 * 8) + o * 8) = __builtin_bit_cast(uint4, v);
    } else if (tid < P1 + P2 + P3 + P4) {
        const int x = tid - (P1 + P2 + P3);
        const float4 a = ((const float4*)fc1w)[x * 2];
        const float4 b = ((const float4*)fc1w)[x * 2 + 1];
        v[0] = f2bs(a.x); v[1] = f2bs(a.y); v[2] = f2bs(a.z); v[3] = f2bs(a.w);
        v[4] = f2bs(b.x); v[5] = f2bs(b.y); v[6] = f2bs(b.z); v[7] = f2bs(b.w);
        *(uint4*)(ws + E1 + E2 + E3 + (size_t)x * 8) = __builtin_bit_cast(uint4, v);
    }
}

// ---------------- CIN layer via 32x32x16 f16 MFMA; block = (b, d-half) -------
// C[d][o] = sum_n A[d][n]*W[n][o], n = k*48+j, A[d][n] = xk[d][k]*x0[d][j].
// n = ks*16 + 8*h2 + i => k = ks/3 (1 xk splat / 3 ksteps), j = (2*(ks%3)+h2)*8+i
// -> 3 fixed half8 q8[] registers per layer. A-build: 4 v_pk_mul_f16 ONLY
// (all A inputs f16: x0h, bufA, bufB). 4 waves = (tile: 2 x 32 rows) x (khalf);
// khalf combine store->barrier->add. B-prefetch: 3-slot rotation.
// NO device-scope fences (per-XCD L2 writeback — R10 regression).
template<int KTOT, int HO, int NT, int HOP, bool WRITEBUF>
__device__ __forceinline__ void cin_mfma(
    const unsigned short* __restrict__ x0h,
    const unsigned short* __restrict__ xksrc, int xkstride,
    const unsigned short* __restrict__ wt,
    unsigned short* __restrict__ outbuf, int outstride,
    float* __restrict__ pool, int poff, int t)
{
    const int lane  = t & 63;
    const int w     = t >> 6;
    const int tile  = w & 1;
    const int khalf = w >> 1;
    const int o0 = lane & 31, h2 = lane >> 5;
    const int dl = tile * 32 + o0;          // this lane's A-row (local d)
    constexpr int KS = KTOT / 16;
    constexpr int KH = KS / 2;
    static_assert(KH % 6 == 0, "K-half must be a multiple of 6 ksteps");
    const int ks0 = khalf * KH;
    const int kb0 = ks0 / 3;

    // x0 j-operands: 3 fixed half8 registers for the whole layer (16B-aligned)
    half8 q8[3];
    #pragma unroll
    for (int p = 0; p < 3; ++p)
        q8[p] = *(const half8*)(x0h + dl * X0S + (2 * p + h2) * 8);

    f32x16 acc[NT];
    #pragma unroll
    for (int nt = 0; nt < NT; ++nt)
        #pragma unroll
        for (int r = 0; r < 16; ++r) acc[nt][r] = 0.f;

    const unsigned short* xkrow = xksrc + dl * xkstride;
    const unsigned short* wb = wt + (size_t)(h2 * HOP + o0) * 8;

    auto xsplat = [&](int k) -> half8 {
        const unsigned int xp = (unsigned int)xkrow[k] * 0x10001u;
        uint4 s; s.x = xp; s.y = xp; s.z = xp; s.w = xp;
        return __builtin_bit_cast(half8, s);
    };

    uint4 br[3][NT];
    auto loadB = [&](int ks, uint4* b) {
        const unsigned short* p = wb + (size_t)ks * (2 * HOP * 8);
        #pragma unroll
        for (int nt = 0; nt < NT; ++nt)
            b[nt] = *(const uint4*)(p + nt * 256);
    };
    auto phase = [&](int p, half8 xs, const uint4* b) {
        const half8 av = xs * q8[p];          // 4 v_pk_mul_f16
        #pragma unroll
        for (int nt = 0; nt < NT; ++nt)
            acc[nt] = __builtin_amdgcn_mfma_f32_32x32x16_f16(
                av, __builtin_bit_cast(half8, b[nt]), acc[nt], 0, 0, 0);
    };

    loadB(ks0 + 0, br[0]);
    loadB(ks0 + 1, br[1]);
    loadB(ks0 + 2, br[2]);
    half8 xs0 = xsplat(kb0);
    #pragma unroll 1
    for (int it = 0; it < KH / 6; ++it) {
        const int g  = ks0 + it * 6;
        const int kb = kb0 + it * 2;
        const half8 xs1 = xsplat(kb + 1);
        phase(0, xs0, br[0]);  loadB(g + 3, br[0]);
        phase(1, xs0, br[1]);  loadB(g + 4, br[1]);
        phase(2, xs0, br[2]);  loadB(g + 5, br[2]);
        const half8 xsn = xsplat(kb + 2);   // in-row-pad at last iter (dead value)
        phase(0, xs1, br[0]);  loadB(g + 6, br[0]);
        phase(1, xs1, br[1]);  loadB(g + 7, br[1]);   // final iter: <=2 ksteps past
        phase(2, xs1, br[2]);  loadB(g + 8, br[2]);   // layer region, inside d_ws
        xs0 = xsn;
    }

    // epilogue: pool partials + khalf=0 stores (f16), barrier, khalf=1 adds
    const int dbase = tile * 32 + 4 * h2;
    #pragma unroll
    for (int nt = 0; nt < NT; ++nt) {
        const int o = nt * 32 + o0;
        if (o < HO) {
            float s = 0.f;
            #pragma unroll
            for (int r = 0; r < 16; ++r) s += acc[nt][r];
            if (WRITEBUF && khalf == 0) {
                #pragma unroll
                for (int r = 0; r < 16; ++r)
                    outbuf[(dbase + (r & 3) + 8 * (r >> 2)) * outstride + o] = f2hs(acc[nt][r]);
            }
            s += __shfl_xor(s, 32, 64);   // combine h2 halves (same o, disjoint rows)
            if (lane < 32) atomicAdd(&pool[poff + o], s);
        }
    }
    if (WRITEBUF) {
        __syncthreads();                  // khalf=0 partials visible
        if (khalf == 1) {
            #pragma unroll
            for (int nt = 0; nt < NT; ++nt) {
                const int o = nt * 32 + o0;
                if (o < HO) {
                    #pragma unroll
                    for (int r = 0; r < 16; ++r) {
                        const int idx = (dbase + (r & 3) + 8 * (r >> 2)) * outstride + o;
                        outbuf[idx] = f2hs(hs2f(outbuf[idx]) + acc[nt][r]);
                    }
                }
            }
        }
        __syncthreads();                  // combined buf visible to next layer
    }
}

__global__ __launch_bounds__(256, 4)
void dcin_kernel(const int*   __restrict__ x,
                 const float* __restrict__ emb,
                 const unsigned short* __restrict__ ws,   // f16/bf16 weights
                 float* __restrict__ wsf)                 // float partial region
{
    __shared__ __align__(16) unsigned short x0h [DH * X0S];   // 7168 B f16 embeds
    __shared__ __align__(16) unsigned short bufA[DH * BAS];   // 8832 B f16 L1 out
    __shared__ __align__(16) unsigned short bufB[DH * BBS];   // 4224 B f16 L2 out
    __shared__ float pool_s[H1 + H2 + H3];
    __shared__ int   sx[M];
    float* const red2 = (float*)bufB;    // 512 floats (2048B <= 4224B), after layer 3

    const unsigned short* wt1  = ws;
    const unsigned short* wt2  = ws + E1;
    const unsigned short* wt3  = ws + E1 + E2;
    const unsigned short* fc1b = ws + E1 + E2 + E3;

    const int b = blockIdx.x >> 1;
    const int h = blockIdx.x & 1;      // d-half
    const int t = threadIdx.x;

    if (t < M) sx[t] = x[b * M + t];
    if (t < H1 + H2 + H3) pool_s[t] = 0.f;
    __syncthreads();

    // gather x0h[dl][j] = f16(emb[sx[j]][h*64+dl]); j-fast writes
    for (int i = t; i < M * (DH / 4); i += 256) {
        const int c = i / 48;              // local float4 index 0..15
        const int j = i - c * 48;
        const float4 v = ((const float4*)(emb + (size_t)sx[j] * D))[h * 16 + c];
        x0h[(4 * c + 0) * X0S + j] = f2hs(v.x);
        x0h[(4 * c + 1) * X0S + j] = f2hs(v.y);
        x0h[(4 * c + 2) * X0S + j] = f2hs(v.z);
        x0h[(4 * c + 3) * X0S + j] = f2hs(v.w);
    }
    __syncthreads();

    // ---- CIN layers (32x32x16 f16 MFMA, f16 A-build) ----
    cin_mfma<K1, H1, 3, HOP1, true >(x0h, x0h,  X0S, wt1, bufA, BAS, pool_s, 0, t);
    cin_mfma<K2, H2, 1, HOP2, true >(x0h, bufA, BAS, wt2, bufB, BBS, pool_s, H1, t);
    cin_mfma<K3, H3, 1, HOP3, false>(x0h, bufB, BBS, wt3, nullptr, 0, pool_s, H1 + H2, t);
    __syncthreads();   // pool complete, bufB (red2 alias) dead

    // ---- fc1 partial for this d-half (bf16 weights, f16 x0), no bias/act ----
    {
        const int u2 = (t & 31) * 2;
        const int part = t >> 5;          // 8 parts x 6 fields
        float a0 = 0.f, a1 = 0.f;
        for (int j = part * 6; j < part * 6 + 6; ++j) {
            const unsigned short* xr = x0h + j;
            #pragma unroll 4
            for (int d = 0; d < DH; ++d) {
                const float xv = hs2f(xr[d * X0S]);
                const unsigned int wp = *(const unsigned int*)(
                    fc1b + (size_t)(j * D + h * DH + d) * 64 + u2);
                a0 = fmaf(xv, __builtin_bit_cast(float, wp << 16), a0);
                a1 = fmaf(xv, __builtin_bit_cast(float, wp & 0xffff0000u), a1);
            }
        }
        red2[t * 2]     = a0;
        red2[t * 2 + 1] = a1;
    }
    __syncthreads();

    // ---- store partials to global ----
    const int slot = b * 2 + h;
    if (t < 64) {
        float v = 0.f;
        #pragma unroll
        for (int p = 0; p < 8; ++p)
            v += red2[(p * 32 + (t >> 1)) * 2 + (t & 1)];
        wsf[OH1P + slot * 64 + t] = v;
    }
    if (t >= 64 && t < 64 + H1 + H2 + H3)
        wsf[OPOOL + slot * 128 + (t - 64)] = pool_s[t - 64];
}

// ---------------- tail: combine halves + fc chain + output -------------------
__global__ __launch_bounds__(64)
void tail_kernel(const int*   __restrict__ x,
                 const float* __restrict__ lin_w, const float* __restrict__ lin_b,
                 const float* __restrict__ fc1_b,
                 const float* __restrict__ bn1_g, const float* __restrict__ bn1_b,
                 const float* __restrict__ fc2_w, const float* __restrict__ fc2_b,
                 const float* __restrict__ bn2_g, const float* __restrict__ bn2_b,
                 const float* __restrict__ fc3_w, const float* __restrict__ fc3_b,
                 const float* __restrict__ bn3_g, const float* __restrict__ bn3_b,
                 const float* __restrict__ out_w, const float* __restrict__ out_b,
                 const float* __restrict__ wsf,
                 float* __restrict__ out)
{
    __shared__ float h1s[64], h2s[48], h3s[24];
    __shared__ float pool_s[H1 + H2 + H3];
    const int b = blockIdx.x;
    const int t = threadIdx.x;
    const int s0 = b * 2, s1 = b * 2 + 1;

    {
        float v = wsf[OH1P + s0 * 64 + t] + wsf[OH1P + s1 * 64 + t] + fc1_b[t];
        v = fmaxf(v, 0.f);
        h1s[t] = bn1_g[t] * v * BN_SCALE + bn1_b[t];
    }
    for (int i = t; i < H1 + H2 + H3; i += 64)
        pool_s[i] = wsf[OPOOL + s0 * 128 + i] + wsf[OPOOL + s1 * 128 + i];
    __syncthreads();

    if (t < 48) {
        float a = fc2_b[t];
        #pragma unroll 4
        for (int u = 0; u < 64; ++u) a = fmaf(h1s[u], fc2_w[u * 48 + t], a);
        a = tanhf(a);
        h2s[t] = bn2_g[t] * a * BN_SCALE + bn2_b[t];
    }
    __syncthreads();

    if (t < 24) {
        float a = fc3_b[t];
        #pragma unroll 4
        for (int u = 0; u < 48; ++u) a = fmaf(h2s[u], fc3_w[u * 24 + t], a);
        a = tanhf(a);
        h3s[t] = bn3_g[t] * a * BN_SCALE + bn3_b[t];
    }
    __syncthreads();

    if (t == 0) {
        float s = lin_b[0];
        for (int j = 0; j < M; ++j) s += (float)x[b * M + j] * lin_w[j];
        const float slin = tanhf(s);
        float z = out_b[0];
        #pragma unroll 4
        for (int i = 0; i < H3; ++i) z = fmaf(h3s[i], out_w[i], z);
        z = fmaf(slin, out_w[H3], z);
        #pragma unroll 4
        for (int i = 0; i < H1 + H2 + H3; ++i)
            z = fmaf(pool_s[i], out_w[H3 + 1 + i], z);
        out[b] = 1.f / (1.f + expf(-z));
    }
}

extern "C" void kernel_launch(void* const* d_in, const int* in_sizes, int n_in,
                              void* d_out, int out_size, void* d_ws, size_t ws_size,
                              hipStream_t stream) {
    (void)in_sizes; (void)n_in; (void)ws_size; (void)out_size;
    const int*   x     = (const int*)  d_in[0];
    const float* emb   = (const float*)d_in[1];
    const float* w1    = (const float*)d_in[2];
    const float* w2    = (const float*)d_in[3];
    const float* w3    = (const float*)d_in[4];
    const float* lin_w = (const float*)d_in[5];
    const float* lin_b = (const float*)d_in[6];
    const float* fc1_w = (const float*)d_in[7];
    const float* fc1_b = (const float*)d_in[8];
    const float* bn1_g = (const float*)d_in[9];
    const float* bn1_b = (const float*)d_in[10];
    const float* fc2_w = (const float*)d_in[11];
    const float* fc2_b = (const float*)d_in[12];
    const float* bn2_g = (const float*)d_in[13];
    const float* bn2_b = (const float*)d_in[14];
    const float* fc3_w = (const float*)d_in[15];
    const float* fc3_b = (const float*)d_in[16];
    const float* bn3_g = (const float*)d_in[17];
    const float* bn3_b = (const float*)d_in[18];
    const float* out_w = (const float*)d_in[19];
    const float* out_b = (const float*)d_in[20];
    unsigned short* ws = (unsigned short*)d_ws;
    float* wsf = (float*)(ws + EW);

    const int prep_threads = P1 + P2 + P3 + P4;
    prep_kernel<<<(prep_threads + 255) / 256, 256, 0, stream>>>(w1, w2, w3, fc1_w, ws);

    dcin_kernel<<<1024, 256, 0, stream>>>(x, emb, ws, wsf);

    tail_kernel<<<512, 64, 0, stream>>>(
        x, lin_w, lin_b, fc1_b, bn1_g, bn1_b,
        fc2_w, fc2_b, bn2_g, bn2_b,
        fc3_w, fc3_b, bn3_g, bn3_b,
        out_w, out_b, wsf, (float*)d_out);
}